// Round 1
// 213.475 us; speedup vs baseline: 1.0214x; 1.0214x over previous
//
#include <hip/hip_runtime.h>
#include <cstdint>

typedef _Float16 half8 __attribute__((ext_vector_type(8)));
typedef __fp16 fp16x2 __attribute__((ext_vector_type(2)));
typedef float f32x4 __attribute__((ext_vector_type(4)));

// ws layout (halfs), per head 2048*64 = 131072 per tensor:
//  Kt: [head] fragment-order: frag(st=s/16, ks) at (st*2+ks)*512 + lane*8,
//      lane(q,l15) 8 halfs = K[16st+l15][32ks+8q+j]           (A-frag for S^T)
//  Vt: [head] sigma-fragment-order: frag(sc=s/32, ct) at (sc*4+ct)*512 + lane*8,
//      lane(q,l15) 8 halfs j = V[16ct+l15][32sc+4q+(j&3)+16(j>>2)]  (A-frag for O)
#define HSTRIDE 131072
#define KOFF    ((size_t)64 * HSTRIDE)
#define VOFF    ((size_t)128 * HSTRIDE)

__device__ __forceinline__ float fast_exp2(float x) {
    return __builtin_amdgcn_exp2f(x);
}

__device__ __forceinline__ uint32_t pkrtz(float a, float b) {
    fp16x2 h = __builtin_amdgcn_cvt_pkrtz(a, b);
    return __builtin_bit_cast(uint32_t, h);
}

__device__ __forceinline__ void load_lds16(const _Float16* g, _Float16* l) {
    auto* g1 = reinterpret_cast<const __attribute__((address_space(1))) uint32_t*>(
        reinterpret_cast<uintptr_t>(g));
    auto* l3 = reinterpret_cast<__attribute__((address_space(3))) uint32_t*>(
        reinterpret_cast<uintptr_t>(l));
    __builtin_amdgcn_global_load_lds(g1, l3, 16, 0, 0);
}

// ---------------- prep: K transpose + V sigma-pack (unchanged) ----------------
__global__ __launch_bounds__(256) void prep_kernel(const float* __restrict__ qkv,
                                                   _Float16* __restrict__ ws)
{
    __shared__ float Lf[64 * 67];        // 16.75 KB (K branch only)

    const int tid  = threadIdx.x;
    const int lane = tid & 63;
    const int wave = tid >> 6;
    const int bid  = blockIdx.x;

    if (bid < 2048) {
        // ---- K ----
        const int head  = (bid >> 5) & 63;
        const int chunk = bid & 31;          // 64-wide s chunk
        const int b4 = head >> 4, h = head & 15;
        const float* src = qkv + (((size_t)(b4 * 3072 + h * 192 + 64)) << 11)
                         + chunk * 64;

#pragma unroll
        for (int k = 0; k < 4; ++k) {
            int idx = k * 256 + tid;
            int c = idx >> 4;
            int t4 = (idx & 15) << 2;
            float4 f = *(const float4*)&src[(((size_t)c) << 11) + t4];
            float* d = &Lf[c * 67 + t4];
            d[0] = f.x; d[1] = f.y; d[2] = f.z; d[3] = f.w;
        }
        __syncthreads();

        const int q = lane >> 4, l15 = lane & 15;
        const int scol = wave * 16 + l15;    // s within chunk
#pragma unroll
        for (int k = 0; k < 2; ++k) {
            uint32_t d[4];
#pragma unroll
            for (int j = 0; j < 4; ++j) {
                float a = Lf[(32 * k + 8 * q + 2 * j) * 67 + scol];
                float b = Lf[(32 * k + 8 * q + 2 * j + 1) * 67 + scol];
                d[j] = pkrtz(a, b);
            }
            size_t off = KOFF + (size_t)head * HSTRIDE
                       + (size_t)((((chunk * 4 + wave) * 2 + k) * 512) + lane * 8);
            *(uint4*)&ws[off] = make_uint4(d[0], d[1], d[2], d[3]);
        }
    } else {
        // ---- V ----
        const int vb = bid - 2048;
        const int head = vb >> 5, chunk = vb & 31;   // 64-s chunk
        const int b4 = head >> 4, h = head & 15;
        const float* src = qkv + (((size_t)(b4 * 3072 + h * 192 + 128)) << 11) + chunk * 64;
        const int q = lane >> 4, cl = lane & 15;
        const int c = wave * 16 + cl;
#pragma unroll
        for (int k = 0; k < 2; ++k) {
            const float* p = &src[((size_t)c << 11) + k * 32 + q * 4];
            float4 f0 = *(const float4*)&p[0];      // s = 4q..4q+3   (j=0..3)
            float4 f1 = *(const float4*)&p[16];     // s = 16+4q..+3  (j=4..7)
            size_t off = VOFF + (size_t)head * HSTRIDE
                       + (size_t)(((chunk * 2 + k) * 4 + wave) * 512 + lane * 8);
            *(uint4*)&ws[off] = make_uint4(pkrtz(f0.x, f0.y), pkrtz(f0.z, f0.w),
                                           pkrtz(f1.x, f1.y), pkrtz(f1.x * 0.f + f1.z, f1.w));
        }
    }
}

// ---------------- flash attention: cross-tile pipelined S/O, MFMA row-sums ----------------
// Round-9 changes vs round-8:
//  * 2-deep pipeline: pf (exp'd P frags) lives across iterations. Iter `it`
//    issues O(it) MFMAs (pf from last iter, ready at once) together with
//    S(it+1) MFMAs; exps trail. Breaks the per-iter serial S->exp->O chain
//    that left both pipes idle ~50% of the time (MfmaUtil 33 / VALUBusy 39).
//    Grid caps occupancy at 2 waves/SIMD -> VGPRs up to 256 are free.
//  * lacc VALU adds (-> ~128 cyc/iter) replaced by 8 MFMA with an all-ones
//    A-frag: Lacc[nt] accumulates column sums of f16 P. Denominator now sums
//    exactly what the numerator consumes (RTZ bias cancels); epilogue shuffles
//    gone.
//  * Sync structure identical to round-8 (waitcnt(0); barrier; stage after),
//    only the prefetch distance changed (stage it+2; tiles it, it+1 resident).
__launch_bounds__(256, 2)
__global__ void attn_kernel(const float* __restrict__ qkv,
                            const _Float16* __restrict__ ws, float* __restrict__ out)
{
    __shared__ __align__(16) _Float16 sK[3][4096];   // 3 x 8 KB, fragment-linear
    __shared__ __align__(16) _Float16 sV[3][4096];   // 3 x 8 KB, fragment-linear

    const int tid  = threadIdx.x;
    const int lane = tid & 63;
    const int wave = tid >> 6;
    const int l15  = lane & 15;
    const int quad = lane >> 4;

    const int bid  = blockIdx.x;
    const int head = bid & 63;
    const int tblk = bid >> 6;
    const int T0   = tblk * 256;
    const int b4   = head >> 4;
    const int h    = head & 15;

    const _Float16* Kt = ws + KOFF + (size_t)head * HSTRIDE;
    const _Float16* Vt = ws + VOFF + (size_t)head * HSTRIDE;
    const float*    Qg = qkv + ((size_t)(b4 * 3072 + h * 192) << 11);
    const float kQ = 0.125f * 1.44269504088896340736f;  // scale^2 * log2(e)

    f32x4 Oacc[4][4];
#pragma unroll
    for (int ct = 0; ct < 4; ++ct)
#pragma unroll
        for (int nt = 0; nt < 4; ++nt) Oacc[ct][nt] = (f32x4)0.f;
    f32x4 Lacc[4];
#pragma unroll
    for (int nt = 0; nt < 4; ++nt) Lacc[nt] = (f32x4)0.f;
    const f32x4 fz = (f32x4)0.f;

    half8 ones;
#pragma unroll
    for (int j = 0; j < 8; ++j) ones[j] = (_Float16)1.0f;

    const int lb = lane * 8;

    auto stage = [&](int buf, int tile) {
        const _Float16* kg = Kt + (size_t)tile * 4096 + wave * 1024 + lane * 8;
        const _Float16* vg = Vt + (size_t)tile * 4096 + wave * 1024 + lane * 8;
        load_lds16(kg,       &sK[buf][wave * 1024]);
        load_lds16(kg + 512, &sK[buf][wave * 1024 + 512]);
        load_lds16(vg,       &sV[buf][wave * 1024]);
        load_lds16(vg + 512, &sV[buf][wave * 1024 + 512]);
    };

    stage(0, 0);   // tiles 0 and 1 in flight before/under the Q gather
    stage(1, 1);

    // Q B-frags: B[k=c=32ks+8q+j][n=t=16nt+l15], direct fp32 gather + scale + pack.
    half8 qb[4][2];
#pragma unroll
    for (int nt = 0; nt < 4; ++nt) {
        const int t = T0 + wave * 64 + nt * 16 + l15;
#pragma unroll
        for (int ks = 0; ks < 2; ++ks) {
            float f[8];
#pragma unroll
            for (int j = 0; j < 8; ++j)
                f[j] = Qg[((size_t)(ks * 32 + quad * 8 + j) << 11) + t];
            uint4 u = make_uint4(pkrtz(f[0] * kQ, f[1] * kQ), pkrtz(f[2] * kQ, f[3] * kQ),
                                 pkrtz(f[4] * kQ, f[5] * kQ), pkrtz(f[6] * kQ, f[7] * kQ));
            qb[nt][ks] = __builtin_bit_cast(half8, u);
        }
    }

    half8 pf[2][4];   // P^T B-frags, live across iterations (pipeline state)

    // S(tile) -> exp -> pf  (A=K, B=Q; sigma k-order)
    auto computeS = [&](const _Float16* sKb) {
        half8 kf[4][2];
#pragma unroll
        for (int mt = 0; mt < 4; ++mt)
#pragma unroll
            for (int ks = 0; ks < 2; ++ks)
                kf[mt][ks] = *(const half8*)&sKb[(mt * 2 + ks) * 512 + lb];
#pragma unroll
        for (int sc2 = 0; sc2 < 2; ++sc2) {
            f32x4 Sa[4], Sb[4];
#pragma unroll
            for (int nt = 0; nt < 4; ++nt) {
                f32x4 t0 = __builtin_amdgcn_mfma_f32_16x16x32_f16(kf[2 * sc2][0], qb[nt][0], fz, 0, 0, 0);
                Sa[nt]   = __builtin_amdgcn_mfma_f32_16x16x32_f16(kf[2 * sc2][1], qb[nt][1], t0, 0, 0, 0);
                f32x4 t1 = __builtin_amdgcn_mfma_f32_16x16x32_f16(kf[2 * sc2 + 1][0], qb[nt][0], fz, 0, 0, 0);
                Sb[nt]   = __builtin_amdgcn_mfma_f32_16x16x32_f16(kf[2 * sc2 + 1][1], qb[nt][1], t1, 0, 0, 0);
            }
#pragma unroll
            for (int nt = 0; nt < 4; ++nt) {
                float e0 = fast_exp2(Sa[nt][0]);
                float e1 = fast_exp2(Sa[nt][1]);
                float e2 = fast_exp2(Sa[nt][2]);
                float e3 = fast_exp2(Sa[nt][3]);
                float e4 = fast_exp2(Sb[nt][0]);
                float e5 = fast_exp2(Sb[nt][1]);
                float e6 = fast_exp2(Sb[nt][2]);
                float e7 = fast_exp2(Sb[nt][3]);
                uint4 u = make_uint4(pkrtz(e0, e1), pkrtz(e2, e3),
                                     pkrtz(e4, e5), pkrtz(e6, e7));
                pf[sc2][nt] = __builtin_bit_cast(half8, u);
            }
        }
    };

    // O += V . P^T ; Lacc += ones . P^T  (row sums of P on the MFMA pipe)
    auto computeO = [&](const _Float16* sVb) {
        half8 vf[2][4];
#pragma unroll
        for (int sc2 = 0; sc2 < 2; ++sc2)
#pragma unroll
            for (int ct = 0; ct < 4; ++ct)
                vf[sc2][ct] = *(const half8*)&sVb[(sc2 * 4 + ct) * 512 + lb];
#pragma unroll
        for (int ct = 0; ct < 4; ++ct)
#pragma unroll
            for (int sc2 = 0; sc2 < 2; ++sc2)
#pragma unroll
                for (int nt = 0; nt < 4; ++nt)
                    Oacc[ct][nt] = __builtin_amdgcn_mfma_f32_16x16x32_f16(
                        vf[sc2][ct], pf[sc2][nt], Oacc[ct][nt], 0, 0, 0);
#pragma unroll
        for (int sc2 = 0; sc2 < 2; ++sc2)
#pragma unroll
            for (int nt = 0; nt < 4; ++nt)
                Lacc[nt] = __builtin_amdgcn_mfma_f32_16x16x32_f16(
                    ones, pf[sc2][nt], Lacc[nt], 0, 0, 0);
    };

    __builtin_amdgcn_s_waitcnt(0);
    __syncthreads();
    computeS(sK[0]);          // prime the pipeline: pf = P(0)

    int bV = 0;               // buffer of tile `it` (tile t lives in buf t%3)
    for (int it = 0; it < 31; ++it) {
        __builtin_amdgcn_s_waitcnt(0);   // own prefetch (tile it+1) resident; own reads retired
        __syncthreads();                 // all waves: tile it+1 complete, buf(it-1) reads done
        if (it < 30) {
            int bs_ = bV + 2; if (bs_ >= 3) bs_ -= 3;
            stage(bs_, it + 2);          // overwrite buf holding tile it-1
        }
        int bK = bV + 1; if (bK >= 3) bK -= 3;
        computeO(sV[bV]);                // O(it): pf ready since last iter
        computeS(sK[bK]);                // S(it+1) -> new pf; exps trail the MFMA block
        bV = bK;
    }

    // peeled tail: O(31). sV[bV] staged at it=29, drained at it=30's barrier;
    // no LDS writes after it=30 -> no barrier needed here.
    computeO(sV[bV]);

    // ---- epilogue: Lacc rows are identical (A=ones) -> no shuffles needed ----
    float inv[4];
#pragma unroll
    for (int nt = 0; nt < 4; ++nt) inv[nt] = 1.f / Lacc[nt][0];

    float* ob = out + (((size_t)(b4 * 1024 + h * 64)) << 11) + T0 + wave * 64;
#pragma unroll
    for (int ct = 0; ct < 4; ++ct)
#pragma unroll
        for (int nt = 0; nt < 4; ++nt) {
            f32x4 o = Oacc[ct][nt];
#pragma unroll
            for (int r = 0; r < 4; ++r)
                ob[((size_t)(ct * 16 + quad * 4 + r) << 11) + nt * 16 + l15] = o[r] * inv[nt];
        }
}

extern "C" void kernel_launch(void* const* d_in, const int* in_sizes, int n_in,
                              void* d_out, int out_size, void* d_ws, size_t ws_size,
                              hipStream_t stream) {
    const float* qkv = (const float*)d_in[0];
    float* out = (float*)d_out;
    _Float16* ws = (_Float16*)d_ws;
    prep_kernel<<<dim3(4096), dim3(256), 0, stream>>>(qkv, ws);
    attn_kernel<<<dim3(512), dim3(256), 0, stream>>>(qkv, ws, out);
}